// Round 21
// baseline (113.601 us; speedup 1.0000x reference)
//
#include <hip/hip_runtime.h>
#include <math.h>

#define PI_F 3.14159265358979323846f

constexpr int Bq = 8, Lq = 1024, Sq = 1024, Hq = 8, Dq = 64;

typedef short short8 __attribute__((ext_vector_type(8)));
typedef _Float16 half8 __attribute__((ext_vector_type(8)));
typedef float f4v __attribute__((ext_vector_type(4)));
typedef unsigned short ushort_t;

static __device__ __forceinline__ f4v mfma16h(half8 a, half8 b, f4v c) {
  return __builtin_amdgcn_mfma_f32_16x16x32_f16(a, b, c, 0, 0, 0);
}
// q~' from q~: pairs (re,im) -> (im,-re); fp16 negate = sign-bit flip
static __device__ __forceinline__ half8 primefh(half8 q) {
  union { half8 h; short8 s; } in, out;
  in.h = q;
#pragma unroll
  for (int i = 0; i < 4; ++i) {
    out.s[2 * i]     = in.s[2 * i + 1];
    out.s[2 * i + 1] = (short)(((ushort_t)in.s[2 * i]) ^ 0x8000u);
  }
  return out.h;
}
static __device__ __forceinline__ unsigned pkh(float a, float b) {
  union { _Float16 h[2]; unsigned u; } p;
  p.h[0] = (_Float16)a; p.h[1] = (_Float16)b;
  return p.u;
}

// ---------------------------------------------------------------------------
// state-math: angles -> diag -> WHT -> st[32] interleaved (re,im) f32
// ---------------------------------------------------------------------------
static __device__ __forceinline__ void state_vec(
    const float* __restrict__ x, const float (*lw)[64], const float* lb,
    int n, float st[32])
{
  const float4* xp = (const float4*)(x + (size_t)n * 64);
  float a0 = lb[0], a1 = lb[1], a2 = lb[2], a3 = lb[3];
#pragma unroll
  for (int i = 0; i < 16; ++i) {
    float4 v = xp[i];
    a0 += v.x * lw[0][4*i] + v.y * lw[0][4*i+1] + v.z * lw[0][4*i+2] + v.w * lw[0][4*i+3];
    a1 += v.x * lw[1][4*i] + v.y * lw[1][4*i+1] + v.z * lw[1][4*i+2] + v.w * lw[1][4*i+3];
    a2 += v.x * lw[2][4*i] + v.y * lw[2][4*i+1] + v.z * lw[2][4*i+2] + v.w * lw[2][4*i+3];
    a3 += v.x * lw[3][4*i] + v.y * lw[3][4*i+1] + v.z * lw[3][4*i+2] + v.w * lw[3][4*i+3];
  }
  a0 = tanhf(a0) * PI_F; a1 = tanhf(a1) * PI_F;
  a2 = tanhf(a2) * PI_F; a3 = tanhf(a3) * PI_F;
  float p01 = a0 * a1, p12 = a1 * a2, p23 = a2 * a3;

  float dr[16], di[16];
#pragma unroll
  for (int d = 0; d < 16; ++d) {
    float s0 = (d & 8) ? -1.f : 1.f;
    float s1 = (d & 4) ? -1.f : 1.f;
    float s2 = (d & 2) ? -1.f : 1.f;
    float s3 = (d & 1) ? -1.f : 1.f;
    float arg = a0*s0 + a1*s1 + a2*s2 + a3*s3
              + p01*s0*s1 + p12*s1*s2 + p23*s2*s3;
    float sn, cs;
    sincosf(0.5f * arg, &sn, &cs);
    dr[d] = cs; di[d] = -sn;
  }
  float hr[16], hi[16];
#pragma unroll
  for (int i = 0; i < 16; ++i) { hr[i] = dr[i]; hi[i] = di[i]; }
#pragma unroll
  for (int stp = 1; stp < 16; stp <<= 1) {
#pragma unroll
    for (int i = 0; i < 16; ++i) {
      if (!(i & stp)) {
        float xr = hr[i], yr = hr[i + stp];
        hr[i] = xr + yr; hr[i + stp] = xr - yr;
        float xi = hi[i], yi = hi[i + stp];
        hi[i] = xi + yi; hi[i + stp] = xi - yi;
      }
    }
  }
#pragma unroll
  for (int d = 0; d < 16; ++d) {
    st[2*d]   = (dr[d] * hr[d] - di[d] * hi[d]) * 0.0625f;
    st[2*d+1] = (dr[d] * hi[d] + di[d] * hr[d]) * 0.0625f;
  }
}

// ---------------------------------------------------------------------------
// k_prep: one launch, three roles by block range.  All outputs FP16.
// ---------------------------------------------------------------------------
__global__ __launch_bounds__(256) void k_prep(
    const float* __restrict__ qin, const float* __restrict__ kin,
    const float* __restrict__ vin,
    const float* __restrict__ wq, const float* __restrict__ bq,
    const float* __restrict__ wk, const float* __restrict__ bk,
    ushort_t* __restrict__ QF, ushort_t* __restrict__ KF,
    ushort_t* __restrict__ VF)
{
  __shared__ float smem[64 * 68];
  int blk = blockIdx.x;
  int t = threadIdx.x;

  if (blk < 512) {
    const bool isQ = (blk < 256);
    const float* x    = isQ ? qin : kin;
    const float* w    = isQ ? wq : wk;
    const float* bias = isQ ? bq : bk;
    float (*lw)[64] = (float(*)[64])smem;
    float* lb = smem + 256;
    lw[t >> 6][t & 63] = w[t];
    if (t < 4) lb[t] = bias[t];
    __syncthreads();

    int n = (blk & 255) * 256 + t;
    float st[32];
    state_vec(x, lw, lb, n, st);
    int b = n >> 13, l = (n >> 3) & 1023, h = n & 7;
    int bh = b * 8 + h;

    unsigned hp[16];
#pragma unroll
    for (int i = 0; i < 16; ++i) hp[i] = pkh(st[2*i], st[2*i+1]);

    if (isQ) {
      size_t rb = ((size_t)bh * Lq + l) * 32;
      uint4* ph = (uint4*)(QF + rb);
#pragma unroll
      for (int i = 0; i < 4; ++i)
        ph[i] = make_uint4(hp[4*i], hp[4*i+1], hp[4*i+2], hp[4*i+3]);
    } else {
      int sf = l >> 4, lh = l & 15;
      size_t fb = (size_t)(bh * 64 + sf) * 512;
#pragma unroll
      for (int g = 0; g < 4; ++g) {
        size_t o = fb + (size_t)((g << 4) + lh) * 8;
        *(uint4*)(KF + o) = make_uint4(hp[4*g], hp[4*g+1], hp[4*g+2], hp[4*g+3]);
      }
    }
  } else {
    // ---- role V ----
    int blk2 = blk - 512;               // 0..1023
    int bh = blk2 >> 4, c = blk2 & 15;
    int b = bh >> 3, h = bh & 7;
    int s0 = c << 6;
    int sl = t >> 2, dq = (t & 3) << 4;
    const float4* src =
        (const float4*)(vin + (((size_t)b * Sq + s0 + sl) * Hq + h) * 64 + dq);
#pragma unroll
    for (int i = 0; i < 4; ++i)
      *(float4*)&smem[sl * 68 + dq + 4 * i] = src[i];
    __syncthreads();
#pragma unroll
    for (int sidx = 0; sidx < 2; ++sidx) {
      int slot = sidx * 256 + t;        // 0..511
      int ks = slot >> 8, f2 = (slot >> 6) & 3, lane = slot & 63;
      int lh = lane & 15, g = lane >> 4;
      int d = f2 * 16 + lh;
      unsigned w4[4];
#pragma unroll
      for (int e2 = 0; e2 < 4; ++e2) {
        int sl0 = ks * 32 + g * 8 + 2 * e2;
        w4[e2] = pkh(smem[sl0 * 68 + d], smem[(sl0 + 1) * 68 + d]);
      }
      size_t off = ((((size_t)(bh * 16 + c) * 2 + ks) * 4 + f2) * 64 + lane) * 8;
      *(uint4*)(VF + off) = make_uint4(w4[0], w4[1], w4[2], w4[3]);
    }
  }
}

// ---------------------------------------------------------------------------
// k_csum: per bh, D = C + J-transform(C) where C = sum_s k~ k~^T (f32).
// rowsum_l = q~^T D q~ (exact identity; J maps (re,im)->(im,-re)).
// 64 blocks x 256 threads; K staged to LDS as f32 in 128-row chunks.
// D[a][b] = C[a][b] + t_a t_b C[a^1][b^1], t_x = (x&1)? +1 : -1.
// ---------------------------------------------------------------------------
__global__ __launch_bounds__(256) void k_csum(
    const ushort_t* __restrict__ KF, float* __restrict__ Cp)
{
  __shared__ float L[128][33];
  __shared__ float Ct[32][33];
  int bh = blockIdx.x;
  int t = threadIdx.x;
  const ushort_t* kb = KF + (size_t)bh * 32768;
  int i = t >> 3, j0 = (t & 7) << 2;
  float c0 = 0.f, c1 = 0.f, c2 = 0.f, c3 = 0.f;

  for (int ch = 0; ch < 8; ++ch) {
    __syncthreads();                    // protect previous chunk reads
    {
      const half8* src = (const half8*)(kb + ch * 4096 + t * 16);
      half8 h0 = src[0], h1 = src[1];
      int sf_l = t >> 5;                // fragment within chunk
      int pr = t & 31;                  // lane pair
      int lane0 = pr * 2, lane1 = lane0 + 1;
      int s0 = sf_l * 16 + (lane0 & 15), d0 = (lane0 >> 4) * 8;
      int s1 = sf_l * 16 + (lane1 & 15), d1 = (lane1 >> 4) * 8;
#pragma unroll
      for (int e = 0; e < 8; ++e) L[s0][d0 + e] = (float)h0[e];
#pragma unroll
      for (int e = 0; e < 8; ++e) L[s1][d1 + e] = (float)h1[e];
    }
    __syncthreads();
#pragma unroll 4
    for (int s = 0; s < 128; ++s) {
      float a = L[s][i];
      c0 += a * L[s][j0 + 0];
      c1 += a * L[s][j0 + 1];
      c2 += a * L[s][j0 + 2];
      c3 += a * L[s][j0 + 3];
    }
  }
  Ct[i][j0 + 0] = c0; Ct[i][j0 + 1] = c1;
  Ct[i][j0 + 2] = c2; Ct[i][j0 + 3] = c3;
  __syncthreads();
  float ta = (i & 1) ? 1.f : -1.f;
  float d4[4];
#pragma unroll
  for (int e = 0; e < 4; ++e) {
    int b = j0 + e;
    float tb = (b & 1) ? 1.f : -1.f;
    d4[e] = Ct[i][b] + ta * tb * Ct[i ^ 1][b ^ 1];
  }
  *(float4*)(Cp + (size_t)bh * 1024 + i * 32 + j0) =
      make_float4(d4[0], d4[1], d4[2], d4[3]);
}

// ---------------------------------------------------------------------------
// k_fidpv11: fused scores+PV, fp16, NO pass-1.
// Prologue: block loads D[bh] (4 KB) to LDS; each thread computes its row's
// rowsum = q^T D q (~270 FMA) + 4-lane shfl reduce -> rinv.
// Main loop = k_fidpv7 pass 2 verbatim (K cross-chunk dbuf, V per-chunk,
// NT attn stores, no block barriers after prologue).
// ---------------------------------------------------------------------------
__global__ __launch_bounds__(256, 4) void k_fidpv11(
    const ushort_t* __restrict__ QF, const ushort_t* __restrict__ KF,
    const ushort_t* __restrict__ VF, const float* __restrict__ Cp,
    float* __restrict__ attn, float* __restrict__ ctx)
{
  __shared__ float Wtr[4][16 * 68];
  __shared__ float Dl[32 * 33];

  int bid = blockIdx.x;                 // 1024 (%8==0 -> bijective swizzle)
  int xcd = bid & 7, idx = bid >> 3;
  int bh = (xcd << 3) | (idx >> 4);
  int l0 = (idx & 15) << 6;
  int t = threadIdx.x;
  int wv = t >> 6, lane = t & 63;
  int lh = lane & 15, g = lane >> 4, ko = g << 3;
  int rowbase = l0 + (wv << 4);

  // ---- prologue: D to LDS, per-row quadratic-form rowsum ----
#pragma unroll
  for (int r = 0; r < 4; ++r) {
    int idxq = r * 256 + t;
    Dl[(idxq >> 5) * 33 + (idxq & 31)] = Cp[(size_t)bh * 1024 + idxq];
  }
  __syncthreads();

  size_t qrowoff = ((size_t)bh * Lq + rowbase + lh) * 32;
  const half8* qrow = (const half8*)(QF + qrowoff);
  float q32[32];
#pragma unroll
  for (int w = 0; w < 4; ++w) {
    half8 hv = qrow[w];
#pragma unroll
    for (int e = 0; e < 8; ++e) q32[w * 8 + e] = (float)hv[e];
  }
  float partial = 0.f;
#pragma unroll
  for (int il = 0; il < 8; ++il) {
    int i = ko + il;
    float y = 0.f;
#pragma unroll
    for (int j = 0; j < 32; ++j) y += Dl[i * 33 + j] * q32[j];
    partial += q32[i] * y;
  }
  partial += __shfl_xor(partial, 16);
  partial += __shfl_xor(partial, 32);
  float rinv = 1.f / (partial + 1e-6f);

  half8 qf  = qrow[g];
  half8 qpf = primefh(qf);

  const ushort_t* gK = KF + (size_t)bh * 32768 + (size_t)lane * 8;
  const ushort_t* gV = VF + (size_t)bh * 65536 + (size_t)lane * 8;

  f4v zero = {0.f, 0.f, 0.f, 0.f};

  // ---- main loop: K dbuf, V per-chunk, NT attn stores ----
  float* abase = attn + ((size_t)bh * Lq + rowbase) * Sq;
  float* wtr = &Wtr[wv][0];
  f4v acc[4] = {zero, zero, zero, zero};

  half8 kA[4], kB[4];
#pragma unroll
  for (int f = 0; f < 4; ++f)
    kA[f] = *(const half8*)(gK + f * 512);

#pragma unroll
  for (int c = 0; c < 16; ++c) {
    const bool even = !(c & 1);
    half8* kcur = even ? kA : kB;
    half8* knxt = even ? kB : kA;
    if (c < 15) {
#pragma unroll
      for (int f = 0; f < 4; ++f)
        knxt[f] = *(const half8*)(gK + ((c + 1) * 4 + f) * 512);
    }
    half8 vb[2][4];
#pragma unroll
    for (int ks = 0; ks < 2; ++ks)
#pragma unroll
      for (int f2 = 0; f2 < 4; ++f2)
        vb[ks][f2] = *(const half8*)(gV + (size_t)(((c*2+ks)*4+f2)) * 512);

#pragma unroll
    for (int f = 0; f < 4; ++f) {
      f4v fr = mfma16h(kcur[f], qf, zero);
      f4v fi = mfma16h(kcur[f], qpf, zero);
      f4v wv4;
#pragma unroll
      for (int r = 0; r < 4; ++r)
        wv4[r] = (fr[r]*fr[r] + fi[r]*fi[r]) * rinv;
      *(f4v*)&wtr[lh * 68 + (f << 4) + (g << 2)] = wv4;
    }
#pragma unroll
    for (int j = 0; j < 4; ++j) {
      int rowp = (j << 2) + g;
      f4v vv = *(const f4v*)&wtr[rowp * 68 + (lh << 2)];
      __builtin_nontemporal_store(
          vv, (f4v*)(abase + (size_t)rowp * Sq + (c << 6) + (lh << 2)));
    }
#pragma unroll
    for (int ks = 0; ks < 2; ++ks) {
      f4v w0 = *(const f4v*)&wtr[lh * 68 + (ks << 5) + ko];
      f4v w1 = *(const f4v*)&wtr[lh * 68 + (ks << 5) + ko + 4];
      half8 wh;
#pragma unroll
      for (int e = 0; e < 4; ++e) wh[e] = (_Float16)w0[e];
#pragma unroll
      for (int e = 0; e < 4; ++e) wh[4 + e] = (_Float16)w1[e];
#pragma unroll
      for (int f2 = 0; f2 < 4; ++f2)
        acc[f2] = mfma16h(wh, vb[ks][f2], acc[f2]);
    }
  }

  // ---- epilogue: ctx stores ----
  int b = bh >> 3, h = bh & 7;
#pragma unroll
  for (int f2 = 0; f2 < 4; ++f2) {
    int d = (f2 << 4) + lh;
#pragma unroll
    for (int r = 0; r < 4; ++r) {
      int l = rowbase + (g << 2) + r;
      ctx[(((size_t)b * Lq + l) * Hq + h) * 64 + d] = acc[f2][r];
    }
  }
}

// ===========================================================================
extern "C" void kernel_launch(void* const* d_in, const int* in_sizes, int n_in,
                              void* d_out, int out_size, void* d_ws, size_t ws_size,
                              hipStream_t stream) {
  const float* q  = (const float*)d_in[0];
  const float* k  = (const float*)d_in[1];
  const float* v  = (const float*)d_in[2];
  const float* wq = (const float*)d_in[3];
  const float* bq = (const float*)d_in[4];
  const float* wk = (const float*)d_in[5];
  const float* bk = (const float*)d_in[6];

  float* out  = (float*)d_out;
  float* ctx  = out;                    // [B,L,H,D]  = 4,194,304 floats
  float* attn = out + 4194304;          // [B,H,L,S]  = 67,108,864 floats

  char* wsb = (char*)d_ws;
  ushort_t* QF = (ushort_t*)(wsb);                              // [0,  4 MB)
  ushort_t* KF = (ushort_t*)(wsb + (size_t)4 * 1024 * 1024);    // [4,  8 MB)
  ushort_t* VF = (ushort_t*)(wsb + (size_t)8 * 1024 * 1024);    // [8, 16 MB)
  float*    Cp = (float*)(wsb + (size_t)16 * 1024 * 1024);      // [16, 16.25 MB)

  hipLaunchKernelGGL(k_prep, dim3(1536), dim3(256), 0, stream,
                     q, k, v, wq, bq, wk, bk, QF, KF, VF);
  hipLaunchKernelGGL(k_csum, dim3(64), dim3(256), 0, stream, KF, Cp);
  hipLaunchKernelGGL(k_fidpv11, dim3(1024), dim3(256), 0, stream,
                     QF, KF, VF, Cp, attn, ctx);
}

// Round 22
// 86.524 us; speedup vs baseline: 1.3129x; 1.3129x over previous
//
#include <hip/hip_runtime.h>
#include <math.h>

#define PI_F 3.14159265358979323846f

constexpr int Bq = 8, Lq = 1024, Sq = 1024, Hq = 8, Dq = 64;

typedef short short8 __attribute__((ext_vector_type(8)));
typedef _Float16 half8 __attribute__((ext_vector_type(8)));
typedef float f4v __attribute__((ext_vector_type(4)));
typedef unsigned short ushort_t;

static __device__ __forceinline__ f4v mfma16h(half8 a, half8 b, f4v c) {
  return __builtin_amdgcn_mfma_f32_16x16x32_f16(a, b, c, 0, 0, 0);
}
// q~' from q~: pairs (re,im) -> (im,-re); fp16 negate = sign-bit flip
static __device__ __forceinline__ half8 primefh(half8 q) {
  union { half8 h; short8 s; } in, out;
  in.h = q;
#pragma unroll
  for (int i = 0; i < 4; ++i) {
    out.s[2 * i]     = in.s[2 * i + 1];
    out.s[2 * i + 1] = (short)(((ushort_t)in.s[2 * i]) ^ 0x8000u);
  }
  return out.h;
}
static __device__ __forceinline__ unsigned pkh(float a, float b) {
  union { _Float16 h[2]; unsigned u; } p;
  p.h[0] = (_Float16)a; p.h[1] = (_Float16)b;
  return p.u;
}

// ---------------------------------------------------------------------------
// state-math: angles -> diag -> WHT -> st[32] interleaved (re,im) f32
// ---------------------------------------------------------------------------
static __device__ __forceinline__ void state_vec(
    const float* __restrict__ x, const float (*lw)[64], const float* lb,
    int n, float st[32])
{
  const float4* xp = (const float4*)(x + (size_t)n * 64);
  float a0 = lb[0], a1 = lb[1], a2 = lb[2], a3 = lb[3];
#pragma unroll
  for (int i = 0; i < 16; ++i) {
    float4 v = xp[i];
    a0 += v.x * lw[0][4*i] + v.y * lw[0][4*i+1] + v.z * lw[0][4*i+2] + v.w * lw[0][4*i+3];
    a1 += v.x * lw[1][4*i] + v.y * lw[1][4*i+1] + v.z * lw[1][4*i+2] + v.w * lw[1][4*i+3];
    a2 += v.x * lw[2][4*i] + v.y * lw[2][4*i+1] + v.z * lw[2][4*i+2] + v.w * lw[2][4*i+3];
    a3 += v.x * lw[3][4*i] + v.y * lw[3][4*i+1] + v.z * lw[3][4*i+2] + v.w * lw[3][4*i+3];
  }
  a0 = tanhf(a0) * PI_F; a1 = tanhf(a1) * PI_F;
  a2 = tanhf(a2) * PI_F; a3 = tanhf(a3) * PI_F;
  float p01 = a0 * a1, p12 = a1 * a2, p23 = a2 * a3;

  float dr[16], di[16];
#pragma unroll
  for (int d = 0; d < 16; ++d) {
    float s0 = (d & 8) ? -1.f : 1.f;
    float s1 = (d & 4) ? -1.f : 1.f;
    float s2 = (d & 2) ? -1.f : 1.f;
    float s3 = (d & 1) ? -1.f : 1.f;
    float arg = a0*s0 + a1*s1 + a2*s2 + a3*s3
              + p01*s0*s1 + p12*s1*s2 + p23*s2*s3;
    float sn, cs;
    sincosf(0.5f * arg, &sn, &cs);
    dr[d] = cs; di[d] = -sn;
  }
  float hr[16], hi[16];
#pragma unroll
  for (int i = 0; i < 16; ++i) { hr[i] = dr[i]; hi[i] = di[i]; }
#pragma unroll
  for (int stp = 1; stp < 16; stp <<= 1) {
#pragma unroll
    for (int i = 0; i < 16; ++i) {
      if (!(i & stp)) {
        float xr = hr[i], yr = hr[i + stp];
        hr[i] = xr + yr; hr[i + stp] = xr - yr;
        float xi = hi[i], yi = hi[i + stp];
        hi[i] = xi + yi; hi[i + stp] = xi - yi;
      }
    }
  }
#pragma unroll
  for (int d = 0; d < 16; ++d) {
    st[2*d]   = (dr[d] * hr[d] - di[d] * hi[d]) * 0.0625f;
    st[2*d+1] = (dr[d] * hi[d] + di[d] * hr[d]) * 0.0625f;
  }
}

// ---------------------------------------------------------------------------
// k_prep: one launch, three roles by block range.  All outputs FP16.
// ---------------------------------------------------------------------------
__global__ __launch_bounds__(256) void k_prep(
    const float* __restrict__ qin, const float* __restrict__ kin,
    const float* __restrict__ vin,
    const float* __restrict__ wq, const float* __restrict__ bq,
    const float* __restrict__ wk, const float* __restrict__ bk,
    ushort_t* __restrict__ QF, ushort_t* __restrict__ KF,
    ushort_t* __restrict__ VF)
{
  __shared__ float smem[64 * 68];
  int blk = blockIdx.x;
  int t = threadIdx.x;

  if (blk < 512) {
    const bool isQ = (blk < 256);
    const float* x    = isQ ? qin : kin;
    const float* w    = isQ ? wq : wk;
    const float* bias = isQ ? bq : bk;
    float (*lw)[64] = (float(*)[64])smem;
    float* lb = smem + 256;
    lw[t >> 6][t & 63] = w[t];
    if (t < 4) lb[t] = bias[t];
    __syncthreads();

    int n = (blk & 255) * 256 + t;
    float st[32];
    state_vec(x, lw, lb, n, st);
    int b = n >> 13, l = (n >> 3) & 1023, h = n & 7;
    int bh = b * 8 + h;

    unsigned hp[16];
#pragma unroll
    for (int i = 0; i < 16; ++i) hp[i] = pkh(st[2*i], st[2*i+1]);

    if (isQ) {
      size_t rb = ((size_t)bh * Lq + l) * 32;
      uint4* ph = (uint4*)(QF + rb);
#pragma unroll
      for (int i = 0; i < 4; ++i)
        ph[i] = make_uint4(hp[4*i], hp[4*i+1], hp[4*i+2], hp[4*i+3]);
    } else {
      int sf = l >> 4, lh = l & 15;
      size_t fb = (size_t)(bh * 64 + sf) * 512;
#pragma unroll
      for (int g = 0; g < 4; ++g) {
        size_t o = fb + (size_t)((g << 4) + lh) * 8;
        *(uint4*)(KF + o) = make_uint4(hp[4*g], hp[4*g+1], hp[4*g+2], hp[4*g+3]);
      }
    }
  } else {
    // ---- role V ----
    int blk2 = blk - 512;               // 0..1023
    int bh = blk2 >> 4, c = blk2 & 15;
    int b = bh >> 3, h = bh & 7;
    int s0 = c << 6;
    int sl = t >> 2, dq = (t & 3) << 4;
    const float4* src =
        (const float4*)(vin + (((size_t)b * Sq + s0 + sl) * Hq + h) * 64 + dq);
#pragma unroll
    for (int i = 0; i < 4; ++i)
      *(float4*)&smem[sl * 68 + dq + 4 * i] = src[i];
    __syncthreads();
#pragma unroll
    for (int sidx = 0; sidx < 2; ++sidx) {
      int slot = sidx * 256 + t;        // 0..511
      int ks = slot >> 8, f2 = (slot >> 6) & 3, lane = slot & 63;
      int lh = lane & 15, g = lane >> 4;
      int d = f2 * 16 + lh;
      unsigned w4[4];
#pragma unroll
      for (int e2 = 0; e2 < 4; ++e2) {
        int sl0 = ks * 32 + g * 8 + 2 * e2;
        w4[e2] = pkh(smem[sl0 * 68 + d], smem[(sl0 + 1) * 68 + d]);
      }
      size_t off = ((((size_t)(bh * 16 + c) * 2 + ks) * 4 + f2) * 64 + lane) * 8;
      *(uint4*)(VF + off) = make_uint4(w4[0], w4[1], w4[2], w4[3]);
    }
  }
}

// ---------------------------------------------------------------------------
// k_fidpv9: fp16 fused scores+PV with BOTH K and V cross-chunk register
// double-buffers.  All loads a chunk consumes are issued BEFORE any store
// of the preceding chunk.  NT attn stores (L2 protection, r17 A/B).
// Best-measured configuration of the session: 87.0 us total.
// ---------------------------------------------------------------------------
__global__ __launch_bounds__(256, 3) void k_fidpv9(
    const ushort_t* __restrict__ QF, const ushort_t* __restrict__ KF,
    const ushort_t* __restrict__ VF, float* __restrict__ attn,
    float* __restrict__ ctx)
{
  __shared__ float Wtr[4][16 * 68];

  int bid = blockIdx.x;                 // 1024 (%8==0 -> bijective swizzle)
  int xcd = bid & 7, idx = bid >> 3;
  int bh = (xcd << 3) | (idx >> 4);
  int l0 = (idx & 15) << 6;
  int t = threadIdx.x;
  int wv = t >> 6, lane = t & 63;
  int lh = lane & 15, g = lane >> 4, ko = g << 3;
  int rowbase = l0 + (wv << 4);

  size_t qoff = ((size_t)bh * Lq + rowbase + lh) * 32 + ko;
  half8 qf  = *(const half8*)(QF + qoff);
  half8 qpf = primefh(qf);

  const ushort_t* gK = KF + (size_t)bh * 32768 + (size_t)lane * 8;
  const ushort_t* gV = VF + (size_t)bh * 65536 + (size_t)lane * 8;

  f4v zero = {0.f, 0.f, 0.f, 0.f};

  // ---- pass 1: rowsum (full fp16 fid — identical math to pass 2) ----
  float rsum = 0.f;
#pragma unroll 8
  for (int sf = 0; sf < 64; ++sf) {
    half8 kf = *(const half8*)(gK + sf * 512);
    f4v fr = mfma16h(kf, qf, zero);
    f4v fi = mfma16h(kf, qpf, zero);
#pragma unroll
    for (int r = 0; r < 4; ++r) rsum += fr[r]*fr[r] + fi[r]*fi[r];
  }
  rsum += __shfl_xor(rsum, 16);
  rsum += __shfl_xor(rsum, 32);
  float rinv = 1.f / (rsum + 1e-6f);

  // ---- pass 2: K and V double-buffered across chunks ----
  float* abase = attn + ((size_t)bh * Lq + rowbase) * Sq;
  float* wtr = &Wtr[wv][0];
  f4v acc[4] = {zero, zero, zero, zero};

  half8 kA[4], kB[4], vA[2][4], vB[2][4];
#pragma unroll
  for (int f = 0; f < 4; ++f)
    kA[f] = *(const half8*)(gK + f * 512);          // chunk 0 K (L2-hot)
#pragma unroll
  for (int ks = 0; ks < 2; ++ks)
#pragma unroll
    for (int f2 = 0; f2 < 4; ++f2)
      vA[ks][f2] = *(const half8*)(gV + (size_t)((ks*4+f2)) * 512);  // chunk 0 V

#pragma unroll
  for (int c = 0; c < 16; ++c) {
    const bool even = !(c & 1);
    half8 (*kcur) = even ? kA : kB;
    half8 (*knxt) = even ? kB : kA;
    half8 (*vcur)[4] = even ? vA : vB;
    half8 (*vnxt)[4] = even ? vB : vA;
    // 1) prefetch next chunk's K AND V — issued BEFORE this chunk's stores,
    //    so next chunk's consumption waits never retire the store stream.
    if (c < 15) {
#pragma unroll
      for (int f = 0; f < 4; ++f)
        knxt[f] = *(const half8*)(gK + ((c + 1) * 4 + f) * 512);
#pragma unroll
      for (int ks = 0; ks < 2; ++ks)
#pragma unroll
        for (int f2 = 0; f2 < 4; ++f2)
          vnxt[ks][f2] = *(const half8*)(gV + (size_t)((((c+1)*2+ks)*4+f2)) * 512);
    }
    // 2) fid on register-resident kcur
#pragma unroll
    for (int f = 0; f < 4; ++f) {
      f4v fr = mfma16h(kcur[f], qf, zero);
      f4v fi = mfma16h(kcur[f], qpf, zero);
      f4v wv4;
#pragma unroll
      for (int r = 0; r < 4; ++r)
        wv4[r] = (fr[r]*fr[r] + fi[r]*fi[r]) * rinv;
      *(f4v*)&wtr[lh * 68 + (f << 4) + (g << 2)] = wv4;
    }
    // 3) transpose readback -> nontemporal coalesced attn stores
#pragma unroll
    for (int j = 0; j < 4; ++j) {
      int rowp = (j << 2) + g;
      f4v vv = *(const f4v*)&wtr[rowp * 68 + (lh << 2)];
      __builtin_nontemporal_store(
          vv, (f4v*)(abase + (size_t)rowp * Sq + (c << 6) + (lh << 2)));
    }
    // 4) PV on register-resident vcur
#pragma unroll
    for (int ks = 0; ks < 2; ++ks) {
      f4v w0 = *(const f4v*)&wtr[lh * 68 + (ks << 5) + ko];
      f4v w1 = *(const f4v*)&wtr[lh * 68 + (ks << 5) + ko + 4];
      half8 wh;
#pragma unroll
      for (int e = 0; e < 4; ++e) wh[e] = (_Float16)w0[e];
#pragma unroll
      for (int e = 0; e < 4; ++e) wh[4 + e] = (_Float16)w1[e];
#pragma unroll
      for (int f2 = 0; f2 < 4; ++f2)
        acc[f2] = mfma16h(wh, vcur[ks][f2], acc[f2]);
    }
  }

  // ---- epilogue: ctx stores ----
  int b = bh >> 3, h = bh & 7;
#pragma unroll
  for (int f2 = 0; f2 < 4; ++f2) {
    int d = (f2 << 4) + lh;
#pragma unroll
    for (int r = 0; r < 4; ++r) {
      int l = rowbase + (g << 2) + r;
      ctx[(((size_t)b * Lq + l) * Hq + h) * 64 + d] = acc[f2][r];
    }
  }
}

// ===========================================================================
extern "C" void kernel_launch(void* const* d_in, const int* in_sizes, int n_in,
                              void* d_out, int out_size, void* d_ws, size_t ws_size,
                              hipStream_t stream) {
  const float* q  = (const float*)d_in[0];
  const float* k  = (const float*)d_in[1];
  const float* v  = (const float*)d_in[2];
  const float* wq = (const float*)d_in[3];
  const float* bq = (const float*)d_in[4];
  const float* wk = (const float*)d_in[5];
  const float* bk = (const float*)d_in[6];

  float* out  = (float*)d_out;
  float* ctx  = out;                    // [B,L,H,D]  = 4,194,304 floats
  float* attn = out + 4194304;          // [B,H,L,S]  = 67,108,864 floats

  char* wsb = (char*)d_ws;
  ushort_t* QF = (ushort_t*)(wsb);                              // [0,  4 MB)
  ushort_t* KF = (ushort_t*)(wsb + (size_t)4 * 1024 * 1024);    // [4,  8 MB)
  ushort_t* VF = (ushort_t*)(wsb + (size_t)8 * 1024 * 1024);    // [8, 16 MB)

  hipLaunchKernelGGL(k_prep, dim3(1536), dim3(256), 0, stream,
                     q, k, v, wq, bq, wk, bk, QF, KF, VF);
  hipLaunchKernelGGL(k_fidpv9, dim3(1024), dim3(256), 0, stream,
                     QF, KF, VF, attn, ctx);
}